// Round 12
// baseline (130.736 us; speedup 1.0000x reference)
//
#include <hip/hip_runtime.h>

typedef _Float16 half8  __attribute__((ext_vector_type(8)));
typedef float    f32x4  __attribute__((ext_vector_type(4)));
typedef float    f32x16 __attribute__((ext_vector_type(16)));

#define T_TOK 16384
#define D_DIM 4096
#define E_EXP 128
#define CAP   256
#define BM    32
#define NT    32   // macro K-steps per pipe, BK=64 each (K per pipe = 2048)

// A LDS per pipe: [buf(2)][row 0..31][256 B]. Per row: h-plane 128 B | m-plane
// 128 B; each plane = 8 chunks of 16 B (8 halfs, k = c*8..+8 of the 64-K step),
// stored at chunk c' = c ^ (row&7). Both ds_write_b128 staging phases and
// ds_read_b128 fragment phases put their 8 lanes on 8 distinct chunks
// (= all 32 banks) -> conflict-free; +128 plane offset preserves banks.
#define A_BUF   8192
#define A_PIPE  16384
#define SMEM_SZ 33792   // 32 KB A tiles + scratch for sm1/sinv; lg aliases

// ---------------------------------------------------------------------------
// Kernel 0: wg (fp32) -> K-substep-tiled split-fp16 planes, scaled by 64.
// Substep s (k=32) block: h plane 8192 B | m plane 8192 B; expert e at e*64 B.
// ---------------------------------------------------------------------------
__global__ __launch_bounds__(256) void prep_wt(
    const float* __restrict__ wg, _Float16* __restrict__ wt)
{
    const int t = blockIdx.x * 256 + threadIdx.x;  // 65536 threads
    const int c = t & 3;
    const int e = (t >> 2) & 127;
    const int s = t >> 9;

    const float* src = wg + (size_t)e * D_DIM + s * 32 + c * 8;
    const f32x4 v0 = *reinterpret_cast<const f32x4*>(src);
    const f32x4 v1 = *reinterpret_cast<const f32x4*>(src + 4);

    half8 h, m;
#pragma unroll
    for (int j = 0; j < 4; j++) {
        float sv = v0[j] * 64.0f;
        _Float16 hh = (_Float16)sv;
        h[j] = hh; m[j] = (_Float16)(sv - (float)hh);
        sv = v1[j] * 64.0f;
        hh = (_Float16)sv;
        h[4 + j] = hh; m[4 + j] = (_Float16)(sv - (float)hh);
    }
    _Float16* dst = wt + (size_t)s * 8192 + e * 32 + c * 8;
    *reinterpret_cast<half8*>(dst)        = h;
    *reinterpret_cast<half8*>(dst + 4096) = m;
}

// ---------------------------------------------------------------------------
// Kernel A: 32x32x16-MFMA dual-K-pipe GEMM + fused gate + idx1 histogram.
// 512 thr = 8 waves = 2 K-pipes x 4 expert-groups (32 experts each).
// Wave tile: 32 rows x 32 experts -> A-LDS amplification 4x (was 8x).
// Issue order per step: B subs 1-3 (L2) FIRST, then A(t+1) (HBM), then
// compute (vmcnt waits only ever cover B), stage A, lgkm-only barrier.
// ---------------------------------------------------------------------------
__global__ __launch_bounds__(512, 4) void gemm_gate(
    const float* __restrict__ x, const _Float16* __restrict__ wt,
    float* __restrict__ out, float* __restrict__ me, int* __restrict__ cnt1)
{
    __shared__ char smem[SMEM_SZ];

    const int tid  = threadIdx.x;
    const int row0 = blockIdx.x * BM;
    const int lane = tid & 63;
    const int w    = tid >> 6;
    const int kp   = w >> 2;     // K-pipe 0/1
    const int wl   = w & 3;      // expert group: experts wl*32 .. +32
    const int col  = lane & 31;  // expert (B) / row (A,C) within tile
    const int k8   = lane >> 5;  // k-span: halfs k8*8 .. +8 of each 16-K sub

    // ---- A staging role: threads 0-255 stage pipe 0, 256-511 pipe 1 ----
    const int sp = tid >> 8;
    const int sr = (tid >> 3) & 31;
    const int sg = tid & 7;
    const float* xA = x + (size_t)(row0 + sr) * D_DIM + sp * 2048 + sg * 8;
    const int awr_h = sp * A_PIPE + sr * 256 + ((sg ^ (sr & 7)) * 16);
    // m plane at +128; + buf*A_BUF

    // ---- A fragment read base: row = lane&31 ----
    const char* const ard = smem + kp * A_PIPE + col * 256;
    const int rsw = col & 7;
    // substep k (K=16), chunk c = k*2 + k8, swizzled c^rsw; m at +128

    // ---- B pointer (halfs): wt step s32 = kp*64 + 2t + (k>>1); +16 if k&1 ----
    const _Float16* const wtB =
        wt + (size_t)(kp * 64) * 8192 + (wl * 32 + col) * 32 + k8 * 8;

    f32x16 acc = (f32x16)0.0f;

#define LOAD_BS(Bh, Bm, t, k)                                                 \
    {                                                                         \
        const _Float16* bp = wtB +                                            \
            (size_t)((2 * (t) + ((k) >> 1)) & 63) * 8192 + ((k) & 1) * 16;    \
        Bh = *reinterpret_cast<const half8*>(bp);                             \
        Bm = *reinterpret_cast<const half8*>(bp + 4096);                      \
    }

#define CONV_WRITE(a0, a1, buf)                                               \
    {                                                                         \
        half8 h, m;                                                           \
        _Pragma("unroll") for (int j = 0; j < 4; j++) {                       \
            _Float16 hh = (_Float16)a0[j];                                    \
            h[j] = hh; m[j] = (_Float16)(a0[j] - (float)hh);                  \
            hh = (_Float16)a1[j];                                             \
            h[4 + j] = hh; m[4 + j] = (_Float16)(a1[j] - (float)hh);          \
        }                                                                     \
        char* const wb = smem + (buf) * A_BUF + awr_h;                        \
        *reinterpret_cast<half8*>(wb)       = h;                              \
        *reinterpret_cast<half8*>(wb + 128) = m;                              \
    }

#define BAR()                                                                 \
    asm volatile("s_waitcnt lgkmcnt(0)" ::: "memory");                        \
    __builtin_amdgcn_sched_barrier(0);                                        \
    __builtin_amdgcn_s_barrier();                                             \
    __builtin_amdgcn_sched_barrier(0);

#define SUB(cur, k, Bh, Bm)                                                   \
    {                                                                         \
        const char* ab = ard + (cur) * A_BUF + ((((k) * 2 + k8) ^ rsw) * 16); \
        const half8 Ah = *reinterpret_cast<const half8*>(ab);                 \
        const half8 Am = *reinterpret_cast<const half8*>(ab + 128);           \
        acc = __builtin_amdgcn_mfma_f32_32x32x16_f16(Am, Bh, acc, 0, 0, 0);   \
        acc = __builtin_amdgcn_mfma_f32_32x32x16_f16(Ah, Bm, acc, 0, 0, 0);   \
        acc = __builtin_amdgcn_mfma_f32_32x32x16_f16(Ah, Bh, acc, 0, 0, 0);   \
    }

// Macro-step t: B(sub1..3) issued first (oldest), then A(t+1) HBM load, then
// compute sub0..3 (waits touch only B), B0 for t+1 mid-step, stage A, barrier.
#define STEP(cur, t)                                                          \
    {                                                                         \
        LOAD_BS(B1h, B1m, t, 1);                                              \
        LOAD_BS(B2h, B2m, t, 2);                                              \
        LOAD_BS(B3h, B3m, t, 3);                                              \
        __builtin_amdgcn_sched_barrier(0);                                    \
        const int kn = (((t) + 1) & (NT - 1)) * 64;                           \
        const f32x4 a0 = *reinterpret_cast<const f32x4*>(xA + kn);            \
        const f32x4 a1 = *reinterpret_cast<const f32x4*>(xA + kn + 4);        \
        __builtin_amdgcn_sched_barrier(0);                                    \
        SUB(cur, 0, B0h, B0m);                                                \
        LOAD_BS(B0h, B0m, (t) + 1, 0);                                        \
        SUB(cur, 1, B1h, B1m);                                                \
        SUB(cur, 2, B2h, B2m);                                                \
        SUB(cur, 3, B3h, B3m);                                                \
        CONV_WRITE(a0, a1, (cur) ^ 1);                                        \
        BAR();                                                                \
    }

    half8 B0h, B0m, B1h, B1m, B2h, B2m, B3h, B3m;

    // ---- prologue: A(0) -> buf0; B(step0, sub0) -> B0 ----
    {
        const f32x4 a0 = *reinterpret_cast<const f32x4*>(xA);
        const f32x4 a1 = *reinterpret_cast<const f32x4*>(xA + 4);
        LOAD_BS(B0h, B0m, 0, 0);
        CONV_WRITE(a0, a1, 0);
        BAR();
    }

    // ---- main loop: 32 macro-steps, 2 per iteration (static indices) ----
    for (int t = 0; t < NT; t += 2) {
        STEP(0, t);
        STEP(1, t + 1);
    }

#undef STEP
#undef SUB
#undef BAR
#undef CONV_WRITE
#undef LOAD_BS

    // ---- merge the two K-pipes into lg (aliases A smem), scale by 1/64 ----
    // C/D layout (m74/m101): col = lane&31, row = (reg&3)+8*(reg>>2)+4*k8.
    float* lg = reinterpret_cast<float*>(smem);   // [32][129]
    if (kp == 1) {
#pragma unroll
        for (int reg = 0; reg < 16; reg++) {
            const int row = (reg & 3) + 8 * (reg >> 2) + 4 * k8;
            lg[row * 129 + wl * 32 + col] = acc[reg] * 0.015625f;
        }
    }
    __syncthreads();
    if (kp == 0) {
#pragma unroll
        for (int reg = 0; reg < 16; reg++) {
            const int row = (reg & 3) + 8 * (reg >> 2) + 4 * k8;
            lg[row * 129 + wl * 32 + col] += acc[reg] * 0.015625f;
        }
    }
    __syncthreads();

    // ---- gate epilogue ----
    float* sm1v  = reinterpret_cast<float*>(smem + 20480);  // [32]
    float* sinvv = sm1v + 32;                               // [32]

    if (tid < BM) {
        const int r = tid;
        const int t = row0 + r;
        float m1 = -1e30f, m2 = -1e30f;
        int   i1 = 0, i2 = 0;
        for (int e = 0; e < E_EXP; e++) {
            const float v = lg[r * 129 + e];
            if (v > m1)      { m2 = m1; i2 = i1; m1 = v; i1 = e; }
            else if (v > m2) { m2 = v; i2 = e; }
        }
        float s = 0.0f;
        for (int e = 0; e < E_EXP; e++) s += __expf(lg[r * 129 + e] - m1);
        const float inv = 1.0f / s;

        out[3 + 0 * T_TOK + t] = (float)i1;
        out[3 + 1 * T_TOK + t] = (float)i2;
        out[3 + 4 * T_TOK + t] = inv;
        out[3 + 5 * T_TOK + t] = __expf(m2 - m1) * inv;
        atomicAdd(&cnt1[i1], 1);
        sm1v[r]  = m1;
        sinvv[r] = inv;
    }
    __syncthreads();

    // parallel exp rewrite: 512 threads x 8 cells
    {
        const int r  = tid & 31;
        const int e0 = (tid >> 5) * 8;
        const float m1 = sm1v[r], inv = sinvv[r];
#pragma unroll
        for (int j = 0; j < 8; j++)
            lg[r * 129 + e0 + j] = __expf(lg[r * 129 + e0 + j] - m1) * inv;
    }
    __syncthreads();

    if (tid < E_EXP) {
        float s = 0.0f;
        for (int r = 0; r < BM; r++) s += lg[r * 129 + tid];
        atomicAdd(&me[tid], s);
    }
}

// ---------------------------------------------------------------------------
// Kernel B: per-expert rank. 256 blocks x 1024 thr: blocks 0-127 scan idx1;
// blocks 128-255 scan idx2 starting at base = cnt1[e] (from gemm histogram).
// ---------------------------------------------------------------------------
__global__ __launch_bounds__(1024) void rank_kernel(
    float* __restrict__ out, const int* __restrict__ cnt1)
{
    const int  e      = blockIdx.x & 127;
    const bool second = blockIdx.x >= 128;
    const int  tid    = threadIdx.x;
    const int  lane   = tid & 63;
    const int  w      = tid >> 6;   // 0..15

    __shared__ int wtot[16];

    const float* idxA = out + 3 + (second ? T_TOK : 0);
    float* loc = out + 3 + (second ? 3 * T_TOK : 2 * T_TOK);

    const unsigned long long below = (1ull << lane) - 1ull;
    int base = second ? cnt1[e] : 0;

    for (int t0 = 0; t0 < T_TOK; t0 += 1024) {
        const int t = t0 + tid;
        const int f = ((int)idxA[t] == e);
        const unsigned long long m = __ballot(f);
        const int pre = __popcll(m & below);
        const int tot = __popcll(m);
        if (lane == 0) wtot[w] = tot;
        __syncthreads();
        int off = 0, all = 0;
#pragma unroll
        for (int i = 0; i < 16; i++) {
            const int v = wtot[i];
            if (i < w) off += v;
            all += v;
        }
        if (f) {
            const int rank = base + off + pre;
            loc[t] = (rank < CAP) ? (float)rank : 0.0f;
        }
        base += all;
        __syncthreads();
    }
}

// ---------------------------------------------------------------------------
// Kernel C: l_aux = sum(me * min(cnt1,CAP)) * E/(T*T); plus constants.
// ---------------------------------------------------------------------------
__global__ __launch_bounds__(128) void finalize_kernel(
    const float* __restrict__ me, const int* __restrict__ cnt1,
    float* __restrict__ out)
{
    __shared__ float red[2];
    const int tid = threadIdx.x;
    const int c = cnt1[tid];
    float p = me[tid] * (float)((c < CAP) ? c : CAP);
#pragma unroll
    for (int o = 32; o > 0; o >>= 1) p += __shfl_down(p, o);
    if ((tid & 63) == 0) red[tid >> 6] = p;
    __syncthreads();
    if (tid == 0) {
        const float tot = red[0] + red[1];
        out[0] = tot * ((float)E_EXP / ((float)T_TOK * (float)T_TOK));
        out[1] = (float)CAP;
        out[2] = (float)E_EXP;
    }
}

extern "C" void kernel_launch(void* const* d_in, const int* in_sizes, int n_in,
                              void* d_out, int out_size, void* d_ws, size_t ws_size,
                              hipStream_t stream)
{
    const float* x  = (const float*)d_in[0];
    const float* wg = (const float*)d_in[1];
    float* out = (float*)d_out;

    float* me   = (float*)d_ws;                      // 128 floats
    int*   cnt1 = (int*)((char*)d_ws + 512);         // 128 ints
    _Float16* wt = (_Float16*)((char*)d_ws + 1024);  // 2 MB K-tiled planes

    hipMemsetAsync(d_ws, 0, 1024, stream);
    prep_wt<<<256, 256, 0, stream>>>(wg, wt);
    gemm_gate<<<T_TOK / BM, 512, 0, stream>>>(x, wt, out, me, cnt1);
    rank_kernel<<<2 * E_EXP, 1024, 0, stream>>>(out, cnt1);
    finalize_kernel<<<1, 128, 0, stream>>>(me, cnt1, out);
}